// Round 11
// baseline (215.425 us; speedup 1.0000x reference)
//
#include <hip/hip_runtime.h>

#define BN 8192      // B*N
#define NP 1024      // N
#define NF 64        // F_OUT
#define NSEG 8192
#define CAP 256      // bucket capacity (deg ~ Poisson(128); P(>256) ~ 1e-8/seg)
#define OVF_MAX 4096

typedef float f32x4 __attribute__((ext_vector_type(4)));

// Fused: blocks [0,nsb) bucket-scatter edges; [nsb,..) dual-MLP (wave/row, shfl bcast)
__global__ __launch_bounds__(256, 8) void prep_kernel(
    const float* __restrict__ x,
    const float* __restrict__ W1, const float* __restrict__ b1,
    const float* __restrict__ W2, const float* __restrict__ b2,
    const float* __restrict__ Ws1, const float* __restrict__ bs1,
    const float* __restrict__ Ws2, const float* __restrict__ bs2,
    const int* __restrict__ eb, const int* __restrict__ ei,
    const int* __restrict__ ej, const int* __restrict__ ek,
    int* __restrict__ cursor, int2* __restrict__ rec,
    int* __restrict__ ovf_cnt, int4* __restrict__ ovf,
    float* __restrict__ x1, float* __restrict__ out,
    int nnz, int nsb)
{
    if ((int)blockIdx.x < nsb) {
        const int e0 = (blockIdx.x * 256 + threadIdx.x) * 4;
        if (e0 < nnz) {
            const int4 b4 = *(const int4*)(eb + e0);
            const int4 i4 = *(const int4*)(ei + e0);
            const int4 j4 = *(const int4*)(ej + e0);
            const int4 k4 = *(const int4*)(ek + e0);
            const int segs[4] = {b4.x * NP + i4.x, b4.y * NP + i4.y,
                                 b4.z * NP + i4.z, b4.w * NP + i4.w};
            const int jks[4]  = {(j4.x << 10) | k4.x, (j4.y << 10) | k4.y,
                                 (j4.z << 10) | k4.z, (j4.w << 10) | k4.w};
            int pos[4];
            #pragma unroll
            for (int c = 0; c < 4; ++c)          // issue all atomics back-to-back
                pos[c] = atomicAdd(&cursor[segs[c]], 1);
            #pragma unroll
            for (int c = 0; c < 4; ++c) {        // then all stores
                if (pos[c] < CAP) {
                    rec[(size_t)segs[c] * CAP + pos[c]] = make_int2(e0 + c, jks[c]);
                } else {
                    const int o = atomicAdd(ovf_cnt, 1);
                    if (o < OVF_MAX) ovf[o] = make_int4(segs[c], e0 + c, jks[c], 0);
                }
            }
        }
    } else {
        // dual MLP: one wave per row, shfl broadcasts, no barriers
        const int row = ((int)blockIdx.x - nsb) * 4 + (threadIdx.x >> 6);
        const int t = threadIdx.x & 63;
        const float xv = x[(size_t)row * NF + t];
        float a1 = b1[t], a2 = bs1[t];
        #pragma unroll 8
        for (int c = 0; c < NF; ++c) {
            const float xc = __shfl(xv, c);
            a1 = fmaf(xc, W1[c * NF + t], a1);
            a2 = fmaf(xc, Ws1[c * NF + t], a2);
        }
        const float h1 = fmaxf(a1, 0.f), h2 = fmaxf(a2, 0.f);
        float o1 = b2[t], o2 = bs2[t];
        #pragma unroll 8
        for (int c = 0; c < NF; ++c) {
            o1 = fmaf(__shfl(h1, c), W2[c * NF + t], o1);
            o2 = fmaf(__shfl(h2, c), Ws2[c * NF + t], o2);
        }
        x1[(size_t)row * NF + t]  = fmaxf(o1, 0.f);
        out[(size_t)row * NF + t] = fmaxf(o2, 0.f);
    }
}

// Wave-per-segment gather: 4 independent waves per block, NO barriers.
__global__ __launch_bounds__(256, 8) void gather_kernel(
    const f32x4* __restrict__ Wv4, const f32x4* __restrict__ x14,
    const int* __restrict__ cursor, const int2* __restrict__ rec,
    const int* __restrict__ ovf_cnt, const int4* __restrict__ ovf,
    f32x4* __restrict__ out4)
{
    __shared__ int2 srec[4][CAP + 4];
    const int w    = threadIdx.x >> 6;
    const int lane = threadIdx.x & 63;
    const int seg  = blockIdx.x * 4 + w;
    const int b    = seg >> 10;
    const int dtrue = cursor[seg];
    const int cnt  = min(dtrue, CAP);
    const int cnt4 = (cnt + 3) & ~3;

    // coalesced stage of this wave's bucket (same-wave LDS dep: no barrier)
    for (int i = lane; i < cnt; i += 64)
        srec[w][i] = rec[(size_t)seg * CAP + i];
    if (lane < cnt4 - cnt)                       // zero-pad to multiple of 4
        srec[w][cnt + lane] = make_int2(0, 0);

    const int sub = lane >> 4;
    const int c16 = lane & 15;
    const f32x4* __restrict__ x1b = x14 + ((size_t)b << 10) * 16;

    f32x4 acc = {0.f, 0.f, 0.f, 0.f};
    #pragma unroll 2
    for (int it = 0; it < cnt4; it += 4) {
        const int idx = it + sub;
        const float m = (idx < cnt) ? 1.f : 0.f;
        const int2 r = srec[w][idx];
        const int j = (r.y >> 10) & 1023, k = r.y & 1023;
        const f32x4 wv = __builtin_nontemporal_load(Wv4 + (size_t)(unsigned)r.x * 16 + c16);
        const f32x4 xj = x1b[j * 16 + c16];
        const f32x4 xk = x1b[k * 16 + c16];
        acc += (m * wv) * (xj * xk);
    }

    // exact overflow path (expected novf == 0)
    const int novf = min(ovf_cnt[0], OVF_MAX);
    if (novf > 0) {
        for (int o = 0; o < novf; ++o) {
            const int4 r = ovf[o];
            if (r.x == seg) {
                const float m = (sub == 0) ? 1.f : 0.f;
                const int j = (r.z >> 10) & 1023, k = r.z & 1023;
                const f32x4 wv = Wv4[(size_t)(unsigned)r.y * 16 + c16];
                acc += (m * wv) * (x1b[j * 16 + c16] * x1b[k * 16 + c16]);
            }
        }
    }

    // combine the 4 sub-groups (lanes ^16, ^32)
    #pragma unroll
    for (int mm = 16; mm < 64; mm <<= 1) {
        acc.x += __shfl_xor(acc.x, mm);
        acc.y += __shfl_xor(acc.y, mm);
        acc.z += __shfl_xor(acc.z, mm);
        acc.w += __shfl_xor(acc.w, mm);
    }

    if (sub == 0) {
        const float a = 1.0f / ((float)dtrue + 1e-10f);
        f32x4 o = out4[(size_t)seg * 16 + c16];
        out4[(size_t)seg * 16 + c16] = o + a * acc;
    }
}

extern "C" void kernel_launch(void* const* d_in, const int* in_sizes, int n_in,
                              void* d_out, int out_size, void* d_ws, size_t ws_size,
                              hipStream_t stream) {
    const float* x   = (const float*)d_in[0];
    const float* Wv  = (const float*)d_in[1];
    const int*   eb  = (const int*)d_in[2];
    const int*   ei  = (const int*)d_in[3];
    const int*   ej  = (const int*)d_in[4];
    const int*   ek  = (const int*)d_in[5];
    const float* W1  = (const float*)d_in[6];
    const float* b1  = (const float*)d_in[7];
    const float* W2  = (const float*)d_in[8];
    const float* b2  = (const float*)d_in[9];
    const float* Ws1 = (const float*)d_in[10];
    const float* bs1 = (const float*)d_in[11];
    const float* Ws2 = (const float*)d_in[12];
    const float* bs2 = (const float*)d_in[13];
    float* out = (float*)d_out;
    const int nnz = in_sizes[2];

    char* ws = (char*)d_ws;
    float* x1    = (float*)ws;                             // 2 MB
    int* cursor  = (int*)(ws + (2 << 20));                 // 32 KB (doubles as degree)
    int* ovf_cnt = cursor + NSEG;                          // 4 B
    int4* ovf    = (int4*)(ws + (2 << 20) + (64 << 10));   // 64 KB
    int2* rec    = (int2*)(ws + (2 << 20) + (128 << 10));  // 16 MB
    f32x4* out2  = (f32x4*)(ws + (64 << 20));              // 2 MB scratch (instrumentation)

    const int nsb = nnz / 1024;    // scatter blocks: 256 thr x 4 edges
    const int nmlp = BN / 4;       // MLP blocks: 4 waves x 1 row

    (void)hipMemsetAsync(cursor, 0, (NSEG + 1) * sizeof(int), stream);
    prep_kernel<<<nsb + nmlp, 256, 0, stream>>>(x, W1, b1, W2, b2, Ws1, bs1, Ws2, bs2,
                                                eb, ei, ej, ek, cursor, rec, ovf_cnt, ovf,
                                                x1, out, nnz, nsb);
    gather_kernel<<<NSEG / 4, 256, 0, stream>>>((const f32x4*)Wv, (const f32x4*)x1,
                                                cursor, rec, ovf_cnt, ovf, (f32x4*)out);
    // Instrumentation: identical second gather into ws scratch. Never validated;
    // Delta(dur_us) vs round 9 == T_gather.
    gather_kernel<<<NSEG / 4, 256, 0, stream>>>((const f32x4*)Wv, (const f32x4*)x1,
                                                cursor, rec, ovf_cnt, ovf, out2);
}

// Round 12
// 163.267 us; speedup vs baseline: 1.3195x; 1.3195x over previous
//
#include <hip/hip_runtime.h>

#define BN 8192      // B*N
#define NP 1024      // N
#define NF 64        // F_OUT
#define NSEG 8192
#define CAP 256      // bucket capacity (deg ~ Poisson(128); P(>256) ~ 1e-8/seg)
#define CPAD 32      // cursor stride: one counter per 128 B line
#define OVF_MAX 4096

typedef float f32x4 __attribute__((ext_vector_type(4)));

// Fused: blocks [0,nsb) bucket-scatter, ONE edge per thread; [nsb,..) dual-MLP.
__global__ __launch_bounds__(256, 8) void prep_kernel(
    const float* __restrict__ x,
    const float* __restrict__ W1, const float* __restrict__ b1,
    const float* __restrict__ W2, const float* __restrict__ b2,
    const float* __restrict__ Ws1, const float* __restrict__ bs1,
    const float* __restrict__ Ws2, const float* __restrict__ bs2,
    const int* __restrict__ eb, const int* __restrict__ ei,
    const int* __restrict__ ej, const int* __restrict__ ek,
    int* __restrict__ cursor, int2* __restrict__ rec,
    int* __restrict__ ovf_cnt, int4* __restrict__ ovf,
    float* __restrict__ x1, float* __restrict__ out,
    int nnz, int nsb)
{
    if ((int)blockIdx.x < nsb) {
        const int e = blockIdx.x * 256 + threadIdx.x;
        if (e < nnz) {
            const int seg = eb[e] * NP + ei[e];
            const int jk = (ej[e] << 10) | ek[e];
            const int pos = atomicAdd(&cursor[seg * CPAD], 1);
            if (pos < CAP) {
                rec[(size_t)seg * CAP + pos] = make_int2(e, jk);
            } else {
                const int o = atomicAdd(ovf_cnt, 1);
                if (o < OVF_MAX) ovf[o] = make_int4(seg, e, jk, 0);
            }
        }
    } else {
        // dual MLP: one wave per row, shfl broadcasts, no barriers
        const int row = ((int)blockIdx.x - nsb) * 4 + (threadIdx.x >> 6);
        const int t = threadIdx.x & 63;
        const float xv = x[(size_t)row * NF + t];
        float a1 = b1[t], a2 = bs1[t];
        #pragma unroll 8
        for (int c = 0; c < NF; ++c) {
            const float xc = __shfl(xv, c);
            a1 = fmaf(xc, W1[c * NF + t], a1);
            a2 = fmaf(xc, Ws1[c * NF + t], a2);
        }
        const float h1 = fmaxf(a1, 0.f), h2 = fmaxf(a2, 0.f);
        float o1 = b2[t], o2 = bs2[t];
        #pragma unroll 8
        for (int c = 0; c < NF; ++c) {
            o1 = fmaf(__shfl(h1, c), W2[c * NF + t], o1);
            o2 = fmaf(__shfl(h2, c), Ws2[c * NF + t], o2);
        }
        x1[(size_t)row * NF + t]  = fmaxf(o1, 0.f);
        out[(size_t)row * NF + t] = fmaxf(o2, 0.f);
    }
}

// Wave-per-segment gather: 4 independent waves per block, NO barriers.
// (Byte-identical structure to round 9; only the cursor stride changed.)
__global__ __launch_bounds__(256, 8) void gather_kernel(
    const f32x4* __restrict__ Wv4, const f32x4* __restrict__ x14,
    const int* __restrict__ cursor, const int2* __restrict__ rec,
    const int* __restrict__ ovf_cnt, const int4* __restrict__ ovf,
    f32x4* __restrict__ out4)
{
    __shared__ int2 srec[4][CAP + 4];
    const int w    = threadIdx.x >> 6;
    const int lane = threadIdx.x & 63;
    const int seg  = blockIdx.x * 4 + w;
    const int b    = seg >> 10;
    const int dtrue = cursor[seg * CPAD];
    const int cnt  = min(dtrue, CAP);
    const int cnt4 = (cnt + 3) & ~3;

    // coalesced stage of this wave's bucket (same-wave LDS dep: no barrier)
    for (int i = lane; i < cnt; i += 64)
        srec[w][i] = rec[(size_t)seg * CAP + i];
    if (lane < cnt4 - cnt)                       // zero-pad to multiple of 4
        srec[w][cnt + lane] = make_int2(0, 0);

    const int sub = lane >> 4;
    const int c16 = lane & 15;
    const f32x4* __restrict__ x1b = x14 + ((size_t)b << 10) * 16;

    f32x4 acc = {0.f, 0.f, 0.f, 0.f};
    #pragma unroll 2
    for (int it = 0; it < cnt4; it += 4) {
        const int idx = it + sub;
        const float m = (idx < cnt) ? 1.f : 0.f;
        const int2 r = srec[w][idx];
        const int j = (r.y >> 10) & 1023, k = r.y & 1023;
        const f32x4 wv = __builtin_nontemporal_load(Wv4 + (size_t)(unsigned)r.x * 16 + c16);
        const f32x4 xj = x1b[j * 16 + c16];
        const f32x4 xk = x1b[k * 16 + c16];
        acc += (m * wv) * (xj * xk);
    }

    // exact overflow path (expected novf == 0)
    const int novf = min(ovf_cnt[0], OVF_MAX);
    if (novf > 0) {
        for (int o = 0; o < novf; ++o) {
            const int4 r = ovf[o];
            if (r.x == seg) {
                const float m = (sub == 0) ? 1.f : 0.f;
                const int j = (r.z >> 10) & 1023, k = r.z & 1023;
                const f32x4 wv = Wv4[(size_t)(unsigned)r.y * 16 + c16];
                acc += (m * wv) * (x1b[j * 16 + c16] * x1b[k * 16 + c16]);
            }
        }
    }

    // combine the 4 sub-groups (lanes ^16, ^32)
    #pragma unroll
    for (int mm = 16; mm < 64; mm <<= 1) {
        acc.x += __shfl_xor(acc.x, mm);
        acc.y += __shfl_xor(acc.y, mm);
        acc.z += __shfl_xor(acc.z, mm);
        acc.w += __shfl_xor(acc.w, mm);
    }

    if (sub == 0) {
        const float a = 1.0f / ((float)dtrue + 1e-10f);
        f32x4 o = out4[(size_t)seg * 16 + c16];
        out4[(size_t)seg * 16 + c16] = o + a * acc;
    }
}

extern "C" void kernel_launch(void* const* d_in, const int* in_sizes, int n_in,
                              void* d_out, int out_size, void* d_ws, size_t ws_size,
                              hipStream_t stream) {
    const float* x   = (const float*)d_in[0];
    const float* Wv  = (const float*)d_in[1];
    const int*   eb  = (const int*)d_in[2];
    const int*   ei  = (const int*)d_in[3];
    const int*   ej  = (const int*)d_in[4];
    const int*   ek  = (const int*)d_in[5];
    const float* W1  = (const float*)d_in[6];
    const float* b1  = (const float*)d_in[7];
    const float* W2  = (const float*)d_in[8];
    const float* b2  = (const float*)d_in[9];
    const float* Ws1 = (const float*)d_in[10];
    const float* bs1 = (const float*)d_in[11];
    const float* Ws2 = (const float*)d_in[12];
    const float* bs2 = (const float*)d_in[13];
    float* out = (float*)d_out;
    const int nnz = in_sizes[2];

    char* ws = (char*)d_ws;
    float* x1    = (float*)ws;                             // 2 MB
    int* cursor  = (int*)(ws + (2 << 20));                 // 8192*32*4 = 1 MB (padded)
    int* ovf_cnt = cursor + NSEG * CPAD;                   // 4 B
    int4* ovf    = (int4*)(ws + (2 << 20) + (1536 << 10)); // 64 KB
    int2* rec    = (int2*)(ws + (4 << 20));                // 16 MB

    const int nsb = (nnz + 255) / 256;   // scatter blocks: 1 edge/thread
    const int nmlp = BN / 4;             // MLP blocks: 4 waves x 1 row

    (void)hipMemsetAsync(cursor, 0, (NSEG * CPAD + 1) * sizeof(int), stream);
    prep_kernel<<<nsb + nmlp, 256, 0, stream>>>(x, W1, b1, W2, b2, Ws1, bs1, Ws2, bs2,
                                                eb, ei, ej, ek, cursor, rec, ovf_cnt, ovf,
                                                x1, out, nnz, nsb);
    gather_kernel<<<NSEG / 4, 256, 0, stream>>>((const f32x4*)Wv, (const f32x4*)x1,
                                                cursor, rec, ovf_cnt, ovf, (f32x4*)out);
}

// Round 13
// 129.364 us; speedup vs baseline: 1.6653x; 1.2621x over previous
//
#include <hip/hip_runtime.h>

#define BN 8192      // B*N
#define NP 1024      // N
#define NF 64        // F_OUT
#define NSEG 8192
#define CAP 256      // bucket capacity; overflow handled exactly
#define NB 256       // counting blocks
#define EPB 4096     // edges per counting block
#define OVF_MAX 4096

typedef float f32x4 __attribute__((ext_vector_type(4)));

// K1: blocks [0,NB) build per-block seg histograms in LDS -> counts[b][*]
//     blocks [NB,..) dual MLP (wave per row, shfl broadcast)
__global__ __launch_bounds__(256) void count_kernel(
    const float* __restrict__ x,
    const float* __restrict__ W1, const float* __restrict__ b1,
    const float* __restrict__ W2, const float* __restrict__ b2,
    const float* __restrict__ Ws1, const float* __restrict__ bs1,
    const float* __restrict__ Ws2, const float* __restrict__ bs2,
    const int* __restrict__ eb, const int* __restrict__ ei,
    int* __restrict__ counts,
    float* __restrict__ x1, float* __restrict__ out, int nnz)
{
    __shared__ int hist[NSEG];
    if ((int)blockIdx.x < NB) {
        const int t = threadIdx.x;
        #pragma unroll
        for (int q = 0; q < 8; ++q)
            *(int4*)(hist + (q * 256 + t) * 4) = make_int4(0, 0, 0, 0);
        __syncthreads();
        const int base = blockIdx.x * EPB;
        #pragma unroll
        for (int q = 0; q < 4; ++q) {
            const int e0 = base + q * 1024 + t * 4;
            if (e0 < nnz) {
                const int4 b4 = *(const int4*)(eb + e0);
                const int4 i4 = *(const int4*)(ei + e0);
                atomicAdd(&hist[b4.x * NP + i4.x], 1);
                atomicAdd(&hist[b4.y * NP + i4.y], 1);
                atomicAdd(&hist[b4.z * NP + i4.z], 1);
                atomicAdd(&hist[b4.w * NP + i4.w], 1);
            }
        }
        __syncthreads();
        int* row = counts + (size_t)blockIdx.x * NSEG;
        #pragma unroll
        for (int q = 0; q < 8; ++q) {
            const int idx = (q * 256 + t) * 4;
            *(int4*)(row + idx) = *(const int4*)(hist + idx);
        }
    } else {
        // dual MLP: one wave per row, shfl broadcasts, no barriers
        const int row = ((int)blockIdx.x - NB) * 4 + (threadIdx.x >> 6);
        const int t = threadIdx.x & 63;
        const float xv = x[(size_t)row * NF + t];
        float a1 = b1[t], a2 = bs1[t];
        #pragma unroll 8
        for (int c = 0; c < NF; ++c) {
            const float xc = __shfl(xv, c);
            a1 = fmaf(xc, W1[c * NF + t], a1);
            a2 = fmaf(xc, Ws1[c * NF + t], a2);
        }
        const float h1 = fmaxf(a1, 0.f), h2 = fmaxf(a2, 0.f);
        float o1 = b2[t], o2 = bs2[t];
        #pragma unroll 8
        for (int c = 0; c < NF; ++c) {
            o1 = fmaf(__shfl(h1, c), W2[c * NF + t], o1);
            o2 = fmaf(__shfl(h2, c), Ws2[c * NF + t], o2);
        }
        x1[(size_t)row * NF + t]  = fmaxf(o1, 0.f);
        out[(size_t)row * NF + t] = fmaxf(o2, 0.f);
    }
}

// K2: per-seg exclusive scan across the 256 block rows (fully coalesced).
__global__ __launch_bounds__(256) void scan_kernel(
    const int* __restrict__ counts,
    int* __restrict__ offs, int* __restrict__ deg, int* __restrict__ ovf_cnt)
{
    const int s = blockIdx.x * 256 + threadIdx.x;   // 8192 threads total
    int run = 0;
    #pragma unroll 16
    for (int b = 0; b < NB; ++b) {
        const int v = counts[(size_t)b * NSEG + s];
        offs[(size_t)b * NSEG + s] = run;
        run += v;
    }
    deg[s] = run;
    if (s == 0) *ovf_cnt = 0;
}

// K3: deterministic scatter. Block's cursor row lives in LDS (atomics are LDS-local);
// global rec position = offs[b][seg] + local append index. No global atomics.
__global__ __launch_bounds__(256) void scatter_kernel(
    const int* __restrict__ eb, const int* __restrict__ ei,
    const int* __restrict__ ej, const int* __restrict__ ek,
    const int* __restrict__ offs,
    int2* __restrict__ rec, int* __restrict__ ovf_cnt, int4* __restrict__ ovf,
    int nnz)
{
    __shared__ int cur[NSEG];
    const int t = threadIdx.x;
    const int* row = offs + (size_t)blockIdx.x * NSEG;
    #pragma unroll
    for (int q = 0; q < 8; ++q) {
        const int idx = (q * 256 + t) * 4;
        *(int4*)(cur + idx) = *(const int4*)(row + idx);
    }
    __syncthreads();
    const int base = blockIdx.x * EPB;
    #pragma unroll
    for (int q = 0; q < 4; ++q) {
        const int e0 = base + q * 1024 + t * 4;
        if (e0 < nnz) {
            const int4 b4 = *(const int4*)(eb + e0);
            const int4 i4 = *(const int4*)(ei + e0);
            const int4 j4 = *(const int4*)(ej + e0);
            const int4 k4 = *(const int4*)(ek + e0);
            const int segs[4] = {b4.x * NP + i4.x, b4.y * NP + i4.y,
                                 b4.z * NP + i4.z, b4.w * NP + i4.w};
            const int jks[4]  = {(j4.x << 10) | k4.x, (j4.y << 10) | k4.y,
                                 (j4.z << 10) | k4.z, (j4.w << 10) | k4.w};
            #pragma unroll
            for (int c = 0; c < 4; ++c) {
                const int pos = atomicAdd(&cur[segs[c]], 1);   // LDS atomic
                if (pos < CAP) {
                    rec[(size_t)segs[c] * CAP + pos] = make_int2(e0 + c, jks[c]);
                } else {
                    const int o = atomicAdd(ovf_cnt, 1);
                    if (o < OVF_MAX) ovf[o] = make_int4(segs[c], e0 + c, jks[c], 0);
                }
            }
        }
    }
}

// Wave-per-segment gather: 4 independent waves per block, NO barriers.
// (Byte-identical structure to round 9.)
__global__ __launch_bounds__(256, 8) void gather_kernel(
    const f32x4* __restrict__ Wv4, const f32x4* __restrict__ x14,
    const int* __restrict__ deg, const int2* __restrict__ rec,
    const int* __restrict__ ovf_cnt, const int4* __restrict__ ovf,
    f32x4* __restrict__ out4)
{
    __shared__ int2 srec[4][CAP + 4];
    const int w    = threadIdx.x >> 6;
    const int lane = threadIdx.x & 63;
    const int seg  = blockIdx.x * 4 + w;
    const int b    = seg >> 10;
    const int dtrue = deg[seg];
    const int cnt  = min(dtrue, CAP);
    const int cnt4 = (cnt + 3) & ~3;

    for (int i = lane; i < cnt; i += 64)
        srec[w][i] = rec[(size_t)seg * CAP + i];
    if (lane < cnt4 - cnt)
        srec[w][cnt + lane] = make_int2(0, 0);

    const int sub = lane >> 4;
    const int c16 = lane & 15;
    const f32x4* __restrict__ x1b = x14 + ((size_t)b << 10) * 16;

    f32x4 acc = {0.f, 0.f, 0.f, 0.f};
    #pragma unroll 2
    for (int it = 0; it < cnt4; it += 4) {
        const int idx = it + sub;
        const float m = (idx < cnt) ? 1.f : 0.f;
        const int2 r = srec[w][idx];
        const int j = (r.y >> 10) & 1023, k = r.y & 1023;
        const f32x4 wv = __builtin_nontemporal_load(Wv4 + (size_t)(unsigned)r.x * 16 + c16);
        const f32x4 xj = x1b[j * 16 + c16];
        const f32x4 xk = x1b[k * 16 + c16];
        acc += (m * wv) * (xj * xk);
    }

    const int novf = min(ovf_cnt[0], OVF_MAX);
    if (novf > 0) {
        for (int o = 0; o < novf; ++o) {
            const int4 r = ovf[o];
            if (r.x == seg) {
                const float m = (sub == 0) ? 1.f : 0.f;
                const int j = (r.z >> 10) & 1023, k = r.z & 1023;
                const f32x4 wv = Wv4[(size_t)(unsigned)r.y * 16 + c16];
                acc += (m * wv) * (x1b[j * 16 + c16] * x1b[k * 16 + c16]);
            }
        }
    }

    #pragma unroll
    for (int mm = 16; mm < 64; mm <<= 1) {
        acc.x += __shfl_xor(acc.x, mm);
        acc.y += __shfl_xor(acc.y, mm);
        acc.z += __shfl_xor(acc.z, mm);
        acc.w += __shfl_xor(acc.w, mm);
    }

    if (sub == 0) {
        const float a = 1.0f / ((float)dtrue + 1e-10f);
        f32x4 o = out4[(size_t)seg * 16 + c16];
        out4[(size_t)seg * 16 + c16] = o + a * acc;
    }
}

extern "C" void kernel_launch(void* const* d_in, const int* in_sizes, int n_in,
                              void* d_out, int out_size, void* d_ws, size_t ws_size,
                              hipStream_t stream) {
    const float* x   = (const float*)d_in[0];
    const float* Wv  = (const float*)d_in[1];
    const int*   eb  = (const int*)d_in[2];
    const int*   ei  = (const int*)d_in[3];
    const int*   ej  = (const int*)d_in[4];
    const int*   ek  = (const int*)d_in[5];
    const float* W1  = (const float*)d_in[6];
    const float* b1  = (const float*)d_in[7];
    const float* W2  = (const float*)d_in[8];
    const float* b2  = (const float*)d_in[9];
    const float* Ws1 = (const float*)d_in[10];
    const float* bs1 = (const float*)d_in[11];
    const float* Ws2 = (const float*)d_in[12];
    const float* bs2 = (const float*)d_in[13];
    float* out = (float*)d_out;
    const int nnz = in_sizes[2];

    char* ws = (char*)d_ws;
    float* x1    = (float*)ws;                             // [0, 2MB)
    int* deg     = (int*)(ws + (2 << 20));                 // 32 KB
    int* ovf_cnt = (int*)(ws + (2 << 20) + (32 << 10));    // 4 B
    int4* ovf    = (int4*)(ws + (2 << 20) + (64 << 10));   // 64 KB
    int* counts  = (int*)(ws + (4 << 20));                 // [4MB, 12MB)
    int* offs    = (int*)(ws + (12 << 20));                // [12MB, 20MB)
    int2* rec    = (int2*)(ws + (20 << 20));               // [20MB, 36MB)

    count_kernel<<<NB + BN / 4, 256, 0, stream>>>(x, W1, b1, W2, b2, Ws1, bs1, Ws2, bs2,
                                                  eb, ei, counts, x1, out, nnz);
    scan_kernel<<<NSEG / 256, 256, 0, stream>>>(counts, offs, deg, ovf_cnt);
    scatter_kernel<<<NB, 256, 0, stream>>>(eb, ei, ej, ek, offs, rec, ovf_cnt, ovf, nnz);
    gather_kernel<<<NSEG / 4, 256, 0, stream>>>((const f32x4*)Wv, (const f32x4*)x1,
                                                deg, rec, ovf_cnt, ovf, (f32x4*)out);
}